// Round 3
// baseline (367.862 us; speedup 1.0000x reference)
//
#include <hip/hip_runtime.h>
#include <math.h>

#define M_NBR 64
#define HID 128
#define HEADS 8
#define HD 16
#define TDIM 64

// Prologue: qbias[c] = t2v(t) @ wq + bq   (shared across all b)
__global__ void t2v_qbias_kernel(const float* __restrict__ t,
                                 const float* __restrict__ t2v_w,
                                 const float* __restrict__ t2v_b,
                                 const float* __restrict__ wq,
                                 const float* __restrict__ bq,
                                 float* __restrict__ qbias)
{
    __shared__ float feat[TDIM];
    const int tid = threadIdx.x;
    if (tid < TDIM) {
        float raw = t[0] * t2v_w[tid] + t2v_b[tid];
        feat[tid] = (tid == 0) ? raw : sinf(raw);
    }
    __syncthreads();
    if (tid < HID) {
        float acc = bq[tid];
        #pragma unroll
        for (int j = 0; j < TDIM; ++j) acc += feat[j] * wq[j*HID + tid];
        qbias[tid] = acc;
    }
}

__global__ __launch_bounds__(256)
void aggr_kernel(const int* __restrict__ nid,
                 const float* __restrict__ qmat,
                 const float* __restrict__ kmat,
                 const float* __restrict__ vmat,
                 const int* __restrict__ neighbors,
                 const float* __restrict__ times,
                 const float* __restrict__ t,
                 const float* __restrict__ t2v_w,
                 const float* __restrict__ t2v_b,
                 const float* __restrict__ wk,
                 const float* __restrict__ bk,
                 const float* __restrict__ wv,
                 const float* __restrict__ bv,
                 const float* __restrict__ qbias,
                 float* __restrict__ out)
{
    __shared__ __align__(16) float s_q[HID];
    __shared__ float s_qproj[TDIM][HEADS];   // qproj[j][h] = wk[j, h-slice] . q_h
    __shared__ float s_qbk[HEADS];           // bk_h . q_h
    __shared__ __align__(16) float s_tnf[M_NBR][TDIM];
    __shared__ float s_sc[HEADS][M_NBR + 1]; // scores, then unnormalized exp
    __shared__ float s_scale[HEADS];         // 1/denom (0 if no valid neighbor)
    __shared__ float s_wtf[HEADS][TDIM];     // attn-weighted time features
    __shared__ float s_vacc[2][HID];
    __shared__ float s_times[M_NBR];
    __shared__ int   s_nbr[M_NBR];

    const int b = blockIdx.x;
    const int tid = threadIdx.x;
    const float tcur = t[0];

    if (tid < M_NBR) {
        s_times[tid] = times[b*M_NBR + tid];
        s_nbr[tid]   = neighbors[b*M_NBR + tid];
    }
    if (tid < HID) {
        s_q[tid] = qmat[(size_t)nid[b]*HID + tid] + qbias[tid];
    }
    __syncthreads();

    // qproj and qbk (per-b precompute, amortizes the 64x128 time-bias matmul)
    for (int o = tid; o < TDIM*HEADS; o += 256) {
        const int j = o >> 3, h = o & 7;
        const float* wrow = wk + j*HID + h*HD;
        const float* qh   = s_q + h*HD;
        float acc = 0.f;
        #pragma unroll
        for (int d = 0; d < HD; ++d) acc += wrow[d] * qh[d];
        s_qproj[j][h] = acc;
    }
    if (tid < HEADS) {
        const float* qh = s_q + tid*HD;
        float acc = 0.f;
        #pragma unroll
        for (int d = 0; d < HD; ++d) acc += bk[tid*HD + d] * qh[d];
        s_qbk[tid] = acc;
    }

    // Time2Vec features for all valid m (zeros for masked m)
    {
        const int j = tid & 63;
        const int w = tid >> 6;
        const float wj = t2v_w[j], bj = t2v_b[j];
        for (int i = 0; i < M_NBR/4; ++i) {
            const int m = w + 4*i;
            const float tm = s_times[m];
            float val = 0.f;
            if (tm <= tcur) {
                const float raw = tm*wj + bj;
                val = (j == 0) ? raw : sinf(raw);
            }
            s_tnf[m][j] = val;
        }
    }
    __syncthreads();

    // scores[h][m] = 0.25*(q_h . kmat[nbr_m]_h + tnf_m . qproj[:,h] + qbk[h])
    #pragma unroll
    for (int iter = 0; iter < 2; ++iter) {
        const int h = tid & 7;
        const int m = (tid >> 3) + 32*iter;
        float sc = -INFINITY;
        if (s_times[m] <= tcur) {          // wave-groups skip masked m: saves gather
            const float4* k4 = reinterpret_cast<const float4*>(
                kmat + (size_t)s_nbr[m]*HID + h*HD);
            const float*  qh = s_q + h*HD;
            float acc = s_qbk[h];
            float4 kk;
            kk = k4[0]; acc += kk.x*qh[0]  + kk.y*qh[1]  + kk.z*qh[2]  + kk.w*qh[3];
            kk = k4[1]; acc += kk.x*qh[4]  + kk.y*qh[5]  + kk.z*qh[6]  + kk.w*qh[7];
            kk = k4[2]; acc += kk.x*qh[8]  + kk.y*qh[9]  + kk.z*qh[10] + kk.w*qh[11];
            kk = k4[3]; acc += kk.x*qh[12] + kk.y*qh[13] + kk.z*qh[14] + kk.w*qh[15];
            const float* tf = s_tnf[m];
            #pragma unroll
            for (int j = 0; j < TDIM; ++j) acc += tf[j] * s_qproj[j][h];
            sc = acc * 0.25f;
        }
        s_sc[h][m] = sc;
    }
    __syncthreads();

    // masked softmax over m per head (32-lane groups, shuffle reduce)
    {
        const int h = tid >> 5;
        const int l = tid & 31;
        const float x0 = s_sc[h][l];
        const float x1 = s_sc[h][l + 32];
        float mx = fmaxf(x0, x1);
        #pragma unroll
        for (int off = 16; off > 0; off >>= 1) mx = fmaxf(mx, __shfl_xor(mx, off));
        const float e0 = (x0 == -INFINITY) ? 0.f : expf(x0 - mx);
        const float e1 = (x1 == -INFINITY) ? 0.f : expf(x1 - mx);
        float sum = e0 + e1;
        #pragma unroll
        for (int off = 16; off > 0; off >>= 1) sum += __shfl_xor(sum, off);
        s_sc[h][l]      = e0;
        s_sc[h][l + 32] = e1;
        if (l == 0) s_scale[h] = (sum > 0.f) ? (1.f / sum) : 0.f;
    }
    __syncthreads();

    // wtf[h][j] = sum_m e[h][m] * tnf[m][j]   (factored time-bias output term)
    {
        const int j = tid & 63;
        const int w = tid >> 6;
        const int h0 = 2*w, h1 = 2*w + 1;
        float a0 = 0.f, a1 = 0.f;
        for (int m = 0; m < M_NBR; ++m) {
            const float tf = s_tnf[m][j];
            a0 += s_sc[h0][m] * tf;
            a1 += s_sc[h1][m] * tf;
        }
        s_wtf[h0][j] = a0;
        s_wtf[h1][j] = a1;
    }

    // v gather accumulation (two m-halves in parallel; masked m skipped)
    {
        const int c = tid & 127;
        const int part = tid >> 7;
        const int h = c >> 4;
        float acc = 0.f;
        for (int mi = 0; mi < 32; ++mi) {
            const int m = part*32 + mi;
            if (s_times[m] <= tcur) {
                acc += s_sc[h][m] * vmat[(size_t)s_nbr[m]*HID + c];
            }
        }
        s_vacc[part][c] = acc;
    }
    __syncthreads();

    if (tid < HID) {
        const int c = tid;
        const int h = c >> 4;
        const float scale = s_scale[h];
        const float validf = (scale > 0.f) ? 1.f : 0.f;
        float acc = s_vacc[0][c] + s_vacc[1][c];
        float tb = 0.f;
        #pragma unroll
        for (int j = 0; j < TDIM; ++j) tb += s_wtf[h][j] * wv[j*HID + c];
        out[b*HID + c] = scale * (acc + tb) + validf * bv[c];
    }
}

extern "C" void kernel_launch(void* const* d_in, const int* in_sizes, int n_in,
                              void* d_out, int out_size, void* d_ws, size_t ws_size,
                              hipStream_t stream) {
    const int*   nid       = (const int*)  d_in[0];
    const float* qmat      = (const float*)d_in[1];
    const float* kmat      = (const float*)d_in[2];
    const float* vmat      = (const float*)d_in[3];
    const int*   neighbors = (const int*)  d_in[4];
    const float* times     = (const float*)d_in[5];
    const float* t         = (const float*)d_in[6];
    const float* t2v_w     = (const float*)d_in[7];
    const float* t2v_b     = (const float*)d_in[8];
    const float* wk        = (const float*)d_in[9];
    const float* bk        = (const float*)d_in[10];
    const float* wq        = (const float*)d_in[11];
    const float* bq        = (const float*)d_in[12];
    const float* wv        = (const float*)d_in[13];
    const float* bv        = (const float*)d_in[14];
    float* out   = (float*)d_out;
    float* qbias = (float*)d_ws;

    hipLaunchKernelGGL(t2v_qbias_kernel, dim3(1), dim3(128), 0, stream,
                       t, t2v_w, t2v_b, wq, bq, qbias);

    const int B = in_sizes[0];   // 8192
    hipLaunchKernelGGL(aggr_kernel, dim3(B), dim3(256), 0, stream,
                       nid, qmat, kmat, vmat, neighbors, times, t,
                       t2v_w, t2v_b, wk, bk, wv, bv, qbias, out);
}